// Round 17
// baseline (240.904 us; speedup 1.0000x reference)
//
#include <hip/hip_runtime.h>
#include <stdint.h>
#include <stddef.h>

// ---------------------------------------------------------------------------
// MultiheadAttentionWithRope  (B=2, S=4096, E=512, H=8, D=64)
// Round 17: (1) V-transpose fused into k_gemm_qkv z=2 epilogue (via dead
// staging LDS) — kills k_transpose_v dispatch + 33MB vtmp round-trip;
// (2) isolated T5 s_setprio around flash MFMA clusters. 7 dispatches.
// ---------------------------------------------------------------------------

#define B_ 2
#define S_ 4096
#define E_ 512
#define H_ 8
#define D_ 64
#define BS_ (B_*S_)      // 8192

typedef __attribute__((ext_vector_type(8)))  short short8;
typedef __attribute__((ext_vector_type(4)))  float f32x4;
typedef __attribute__((ext_vector_type(16))) float f32x16;
typedef __attribute__((ext_vector_type(4)))  int   i32x4;

#define DEVFN static __device__ __forceinline__

DEVFN short f2bf(float x) {                 // f32 -> bf16 bits, RNE
    unsigned u = __builtin_bit_cast(unsigned, x);
    u += 0x7fffu + ((u >> 16) & 1u);
    return (short)(u >> 16);
}

// ---------------------------------------------------------------------------
// cos/sin table [S][256] float2, computed in double (angle error << f32 ref)
// ---------------------------------------------------------------------------
__global__ void k_cstable(float2* __restrict__ cs) {
    int pos = blockIdx.x;        // 0..4095
    int i   = threadIdx.x;       // 0..255
    double ang = (double)pos * exp(-0.035977892078031968 * (double)i);
    cs[pos * 256 + i] = make_float2((float)cos(ang), (float)sin(ang));
}

// ---------------------------------------------------------------------------
// RoPE both q and k in one dispatch: blockIdx.y selects stream.
// ---------------------------------------------------------------------------
__global__ void k_rope2(const float* __restrict__ q, const float* __restrict__ k,
                        const float2* __restrict__ cs,
                        short* __restrict__ Aq, short* __restrict__ Ak) {
    int row = blockIdx.x;        // 0..8191 (b*S+s)
    int i   = threadIdx.x;       // pair index 0..255
    const float* x   = blockIdx.y ? k  : q;
    short*       out = blockIdx.y ? Ak : Aq;
    int s = row & (S_ - 1);
    float2 c = cs[s * 256 + i];
    float x1 = x[(size_t)row * E_ + 2 * i];
    float x2 = x[(size_t)row * E_ + 2 * i + 1];
    float r1 = x1 * c.x - x2 * c.y;
    float r2 = x1 * c.y + x2 * c.x;
    unsigned pk = ((unsigned)(unsigned short)f2bf(r1)) |
                  (((unsigned)(unsigned short)f2bf(r2)) << 16);
    *reinterpret_cast<unsigned*>(out + (size_t)row * E_ + 2 * i) = pk;
}

// ---------------------------------------------------------------------------
// all three f32->bf16 casts in one segmented dispatch
// ---------------------------------------------------------------------------
#define NV8  (BS_ * E_ / 8)        // 524288
#define NW18 (3 * E_ * E_ / 8)     //  98304
#define NW28 (E_ * E_ / 8)         //  32768
__global__ void k_cast3(const float* __restrict__ v, const float* __restrict__ in_w,
                        const float* __restrict__ out_w,
                        short* __restrict__ Av, short* __restrict__ Wall,
                        short* __restrict__ Wo) {
    int i = blockIdx.x * 256 + threadIdx.x;
    const float* src; short* dst; int j;
    if (i < NV8)               { src = v;     dst = Av;   j = i; }
    else if (i < NV8 + NW18)   { src = in_w;  dst = Wall; j = i - NV8; }
    else if (i < NV8 + NW18 + NW28) { src = out_w; dst = Wo; j = i - NV8 - NW18; }
    else return;
    f32x4 a = *reinterpret_cast<const f32x4*>(src + (size_t)j * 8);
    f32x4 b = *reinterpret_cast<const f32x4*>(src + (size_t)j * 8 + 4);
    short8 o;
#pragma unroll
    for (int t = 0; t < 4; t++) { o[t] = f2bf(a[t]); o[4 + t] = f2bf(b[t]); }
    *reinterpret_cast<short8*>(dst + (size_t)j * 8) = o;
}

// ---------------------------------------------------------------------------
// Batched QKV projection GEMM: one dispatch, blockIdx.z in {0,1,2}.
// z=0: Qh [b,h,s,64] (0.125*log2e scale); z=1: Kh [b,h,s,64];
// z=2: Vt [b,h,d,s] DIRECTLY (transpose via dead staging LDS in epilogue).
// ---------------------------------------------------------------------------
__global__ __launch_bounds__(256) void k_gemm_qkv(
    const short* __restrict__ Aq, const short* __restrict__ Ak,
    const short* __restrict__ Av, const short* __restrict__ Wall,
    const float* __restrict__ in_b,
    short* __restrict__ Qh, short* __restrict__ Kh, short* __restrict__ Vt) {
    __shared__ short smem2[2][128 * 72];   // sA / sB; reused as 128x144 tr tile
    short* sA = smem2[0];
    short* sB = smem2[1];
    int z = blockIdx.z;
    const short* A  = (z == 0) ? Aq : (z == 1) ? Ak : Av;
    const short* Bw = Wall + (size_t)z * E_ * E_;
    const float* bias = in_b + z * E_;
    int tid = threadIdx.x;
    int lane = tid & 63, wv = tid >> 6;
    int lane16 = lane & 15, lgrp = lane >> 4;
    int row0 = blockIdx.y * 128;
    int col0 = blockIdx.x * 128;
    int wr = (wv >> 1) * 64, wc = (wv & 1) * 64;

    f32x4 acc[4][4];
#pragma unroll
    for (int i = 0; i < 4; i++)
#pragma unroll
        for (int j = 0; j < 4; j++)
#pragma unroll
            for (int r = 0; r < 4; r++) acc[i][j][r] = 0.f;

    for (int kt = 0; kt < 8; ++kt) {
        short8 va[4], vb[4];
#pragma unroll
        for (int i = 0; i < 4; i++) {
            int ch = i * 256 + tid;
            int r = ch >> 3, ce = (ch & 7) * 8;
            va[i] = *reinterpret_cast<const short8*>(A  + (size_t)(row0 + r) * E_ + kt * 64 + ce);
            vb[i] = *reinterpret_cast<const short8*>(Bw + (size_t)(col0 + r) * E_ + kt * 64 + ce);
        }
        __syncthreads();
#pragma unroll
        for (int i = 0; i < 4; i++) {
            int ch = i * 256 + tid;
            int r = ch >> 3, ce = (ch & 7) * 8;
            *reinterpret_cast<short8*>(sA + r * 72 + ce) = va[i];
            *reinterpret_cast<short8*>(sB + r * 72 + ce) = vb[i];
        }
        __syncthreads();
#pragma unroll
        for (int ks = 0; ks < 2; ++ks) {
            short8 af[4];
#pragma unroll
            for (int i = 0; i < 4; i++)
                af[i] = *reinterpret_cast<const short8*>(sA + (wr + i * 16 + lane16) * 72 + ks * 32 + lgrp * 8);
#pragma unroll
            for (int j = 0; j < 4; j++) {
                short8 bf = *reinterpret_cast<const short8*>(sB + (wc + j * 16 + lane16) * 72 + ks * 32 + lgrp * 8);
#pragma unroll
                for (int i = 0; i < 4; i++)
                    acc[i][j] = __builtin_amdgcn_mfma_f32_16x16x32_bf16(af[i], bf, acc[i][j], 0, 0, 0);
            }
        }
    }
    if (z == 2) {
        // ---- transpose epilogue: C^T through LDS, coalesced Vt[d][s] stores
        __syncthreads();                       // staging buffers now dead
        short* tr = &smem2[0][0];              // 128 x 144 (stride pad)
#pragma unroll
        for (int i = 0; i < 4; i++) {
#pragma unroll
            for (int j = 0; j < 4; j++) {
                int cl = wc + j * 16 + lane16;
                float bv = bias[col0 + cl];
#pragma unroll
                for (int r = 0; r < 4; r++) {
                    int rl = wr + i * 16 + lgrp * 4 + r;
                    tr[cl * 144 + rl] = f2bf(acc[i][j][r] + bv);
                }
            }
        }
        __syncthreads();
        {
            int el = tid >> 1, shalf = (tid & 1) * 64;     // e-row, s-half
            int colg = col0 + el;
            int h = colg >> 6, d = colg & 63;
            int b = row0 >> 12, s0 = row0 & (S_ - 1);
            size_t dst = ((size_t)(b * H_ + h) * D_ + d) * S_ + s0 + shalf;
#pragma unroll
            for (int jj = 0; jj < 8; jj++) {
                short8 vv = *reinterpret_cast<const short8*>(tr + el * 144 + shalf + jj * 8);
                *reinterpret_cast<short8*>(Vt + dst + jj * 8) = vv;
            }
        }
        return;
    }
#pragma unroll
    for (int i = 0; i < 4; i++) {
#pragma unroll
        for (int j = 0; j < 4; j++) {
            int col = col0 + wc + j * 16 + lane16;
            float bv = bias[col];
#pragma unroll
            for (int r = 0; r < 4; r++) {
                int row = row0 + wr + i * 16 + lgrp * 4 + r;
                float vx = acc[i][j][r] + bv;
                int b = row >> 12, s = row & (S_ - 1);
                int h = col >> 6, d = col & 63;
                if (z == 0) {
                    vx *= 0.18033688011112042f;   // 0.125 * log2(e)
                    Qh[((size_t)(b * H_ + h) * S_ + s) * D_ + d] = f2bf(vx);
                } else {
                    Kh[((size_t)(b * H_ + h) * S_ + s) * D_ + d] = f2bf(vx);
                }
            }
        }
    }
}

// ---------------------------------------------------------------------------
// out-proj GEMM (f32 out)
// ---------------------------------------------------------------------------
__global__ __launch_bounds__(256) void k_gemm_out(
    const short* __restrict__ A, const short* __restrict__ Bw,
    const float* __restrict__ bias, float* __restrict__ out_f) {
    __shared__ short sA[128 * 72];
    __shared__ short sB[128 * 72];
    int tid = threadIdx.x;
    int lane = tid & 63, wv = tid >> 6;
    int lane16 = lane & 15, lgrp = lane >> 4;
    int row0 = blockIdx.y * 128;
    int col0 = blockIdx.x * 128;
    int wr = (wv >> 1) * 64, wc = (wv & 1) * 64;

    f32x4 acc[4][4];
#pragma unroll
    for (int i = 0; i < 4; i++)
#pragma unroll
        for (int j = 0; j < 4; j++)
#pragma unroll
            for (int r = 0; r < 4; r++) acc[i][j][r] = 0.f;

    for (int kt = 0; kt < 8; ++kt) {
        short8 va[4], vb[4];
#pragma unroll
        for (int i = 0; i < 4; i++) {
            int ch = i * 256 + tid;
            int r = ch >> 3, ce = (ch & 7) * 8;
            va[i] = *reinterpret_cast<const short8*>(A  + (size_t)(row0 + r) * E_ + kt * 64 + ce);
            vb[i] = *reinterpret_cast<const short8*>(Bw + (size_t)(col0 + r) * E_ + kt * 64 + ce);
        }
        __syncthreads();
#pragma unroll
        for (int i = 0; i < 4; i++) {
            int ch = i * 256 + tid;
            int r = ch >> 3, ce = (ch & 7) * 8;
            *reinterpret_cast<short8*>(sA + r * 72 + ce) = va[i];
            *reinterpret_cast<short8*>(sB + r * 72 + ce) = vb[i];
        }
        __syncthreads();
#pragma unroll
        for (int ks = 0; ks < 2; ++ks) {
            short8 af[4];
#pragma unroll
            for (int i = 0; i < 4; i++)
                af[i] = *reinterpret_cast<const short8*>(sA + (wr + i * 16 + lane16) * 72 + ks * 32 + lgrp * 8);
#pragma unroll
            for (int j = 0; j < 4; j++) {
                short8 bf = *reinterpret_cast<const short8*>(sB + (wc + j * 16 + lane16) * 72 + ks * 32 + lgrp * 8);
#pragma unroll
                for (int i = 0; i < 4; i++)
                    acc[i][j] = __builtin_amdgcn_mfma_f32_16x16x32_bf16(af[i], bf, acc[i][j], 0, 0, 0);
            }
        }
    }
#pragma unroll
    for (int i = 0; i < 4; i++) {
#pragma unroll
        for (int j = 0; j < 4; j++) {
            int col = col0 + wc + j * 16 + lane16;
            float bv = bias[col];
#pragma unroll
            for (int r = 0; r < 4; r++) {
                int row = row0 + wr + i * 16 + lgrp * 4 + r;
                out_f[(size_t)row * E_ + col] = acc[i][j][r] + bv;
            }
        }
    }
}

// ---------------------------------------------------------------------------
// flash (r12 form + isolated T5 setprio): fixed-max, reg-staged dbuf LDS.
// ---------------------------------------------------------------------------
DEVFN short8 lds_rd(const short* buf, int row, int colb) {
    return *reinterpret_cast<const short8*>(
        (const char*)buf + row * 128 + (colb ^ ((row & 7) << 4)));
}

__global__ __launch_bounds__(256) void k_flash(
    const short* __restrict__ Qh, const short* __restrict__ Kh,
    const short* __restrict__ Vt, short* __restrict__ ctxb,
    float* __restrict__ Lrow) {
    __shared__ short kbuf[2][64 * 64];     // 16 KB
    __shared__ short vbuf[2][64 * 64];     // 16 KB
    __shared__ short ob[4][32 * 72];       // 18 KB epilogue transpose
    int tid = threadIdx.x, lane = tid & 63, wv = tid >> 6;
    int l31 = lane & 31, hi = lane >> 5;
    int gid = blockIdx.x;
    int qt = gid & 31, h = (gid >> 5) & 7, b = gid >> 8;
    int bh = b * H_ + h;
    int qrow0 = qt * 128 + wv * 32;
    const short* Qp = Qh + ((size_t)bh * S_ + qrow0) * D_;
    const short* Kp = Kh + (size_t)bh * S_ * D_;
    const short* Vp = Vt + (size_t)bh * 64 * S_;

    short8 qf[4];
#pragma unroll
    for (int ds = 0; ds < 4; ds++)
        qf[ds] = *reinterpret_cast<const short8*>(
            Qp + (size_t)l31 * D_ + ds * 16 + hi * 8);

    f32x16 ctx0, ctx1;
#pragma unroll
    for (int r = 0; r < 16; r++) { ctx0[r] = 0.f; ctx1[r] = 0.f; }
    float lsum = 0.f;

    int srow = wv * 16 + (lane >> 3);            // +ci*8
    int scol = (lane & 7) * 8;                   // shorts
    int swz  = (scol * 2) ^ ((lane >> 3) << 4);  // swizzled byte col

    short8 kst[2], vst[2];
#define STAGE_LOAD(kb_) do {                                                     \
    int nb_ = (kb_);                                                             \
    _Pragma("unroll") for (int ci = 0; ci < 2; ci++) {                           \
        int r_ = srow + ci * 8;                                                  \
        kst[ci] = *reinterpret_cast<const short8*>(Kp + (size_t)(nb_ + r_) * D_ + scol); \
        vst[ci] = *reinterpret_cast<const short8*>(Vp + (size_t)r_ * S_ + nb_ + scol);   \
    } } while (0)
#define STAGE_WRITE(d_) do {                                                     \
    _Pragma("unroll") for (int ci = 0; ci < 2; ci++) {                           \
        int r_ = srow + ci * 8;                                                  \
        *reinterpret_cast<short8*>((char*)kbuf[d_] + r_ * 128 + swz) = kst[ci];  \
        *reinterpret_cast<short8*>((char*)vbuf[d_] + r_ * 128 + swz) = vst[ci];  \
    } } while (0)

    STAGE_LOAD(0);
    STAGE_WRITE(0);
    __syncthreads();
    int cur = 0;

    for (int kt = 0; kt < 64; ++kt) {
        if (kt < 63) STAGE_LOAD((kt + 1) * 64);   // T14: issue early

        f32x16 s0, s1;
#pragma unroll
        for (int r = 0; r < 16; r++) { s0[r] = 0.f; s1[r] = 0.f; }
        __builtin_amdgcn_s_setprio(1);
#pragma unroll
        for (int ds = 0; ds < 4; ds++) {
            short8 k0 = lds_rd(kbuf[cur], l31,      ds * 32 + hi * 16);
            short8 k1 = lds_rd(kbuf[cur], 32 + l31, ds * 32 + hi * 16);
            s0 = __builtin_amdgcn_mfma_f32_32x32x16_bf16(k0, qf[ds], s0, 0, 0, 0);
            s1 = __builtin_amdgcn_mfma_f32_32x32x16_bf16(k1, qf[ds], s1, 0, 0, 0);
        }
        __builtin_amdgcn_s_setprio(0);
#pragma unroll
        for (int r = 0; r < 16; r++) { s0[r] = __builtin_amdgcn_exp2f(s0[r]); lsum += s0[r]; }
#pragma unroll
        for (int r = 0; r < 16; r++) { s1[r] = __builtin_amdgcn_exp2f(s1[r]); lsum += s1[r]; }

        int w[16];
#pragma unroll
        for (int t = 0; t < 8; t++) {
            asm("v_cvt_pk_bf16_f32 %0, %1, %2" : "=v"(w[t])     : "v"(s0[2 * t]), "v"(s0[2 * t + 1]));
            asm("v_cvt_pk_bf16_f32 %0, %1, %2" : "=v"(w[8 + t]) : "v"(s1[2 * t]), "v"(s1[2 * t + 1]));
        }
        short8 pf[4];
#pragma unroll
        for (int g = 0; g < 4; g++) {
            int a0 = w[g * 4 + 0], b0 = w[g * 4 + 2];
            int a1 = w[g * 4 + 1], b1 = w[g * 4 + 3];
            asm("v_permlane32_swap_b32 %0, %1" : "+v"(a0), "+v"(b0));
            asm("v_permlane32_swap_b32 %0, %1" : "+v"(a1), "+v"(b1));
            i32x4 t4 = {a0, a1, b0, b1};
            pf[g] = __builtin_bit_cast(short8, t4);
        }
        __builtin_amdgcn_s_setprio(1);
#pragma unroll
        for (int ks = 0; ks < 4; ks++) {
            short8 v0 = lds_rd(vbuf[cur], l31,      ks * 32 + hi * 16);
            short8 v1 = lds_rd(vbuf[cur], 32 + l31, ks * 32 + hi * 16);
            ctx0 = __builtin_amdgcn_mfma_f32_32x32x16_bf16(v0, pf[ks], ctx0, 0, 0, 0);
            ctx1 = __builtin_amdgcn_mfma_f32_32x32x16_bf16(v1, pf[ks], ctx1, 0, 0, 0);
        }
        __builtin_amdgcn_s_setprio(0);
        if (kt < 63) STAGE_WRITE(cur ^ 1);        // T14: write late
        __syncthreads();
        cur ^= 1;
    }

    float l_run = lsum + __shfl_xor(lsum, 32);
    float invl = 1.0f / l_run;
    short* obw = &ob[wv][0];
#pragma unroll
    for (int n = 0; n < 2; n++) {
#pragma unroll
        for (int t = 0; t < 8; t++) {
            float a  = (n ? ctx1[2 * t]     : ctx0[2 * t])     * invl;
            float bb = (n ? ctx1[2 * t + 1] : ctx0[2 * t + 1]) * invl;
            int wd;
            asm("v_cvt_pk_bf16_f32 %0, %1, %2" : "=v"(wd) : "v"(a), "v"(bb));
            int d = n * 32 + ((2 * t) & 3) + 8 * ((2 * t) >> 2) + 4 * hi;
            *reinterpret_cast<int*>(obw + l31 * 72 + d) = wd;
        }
    }
    __syncthreads();
    {
        int q = lane >> 1, half = lane & 1;
        size_t gbase = ((size_t)b * S_ + qrow0 + q) * E_ + h * 64 + half * 32;
#pragma unroll
        for (int j = 0; j < 4; j++) {
            short8 vvv = *reinterpret_cast<const short8*>(obw + q * 72 + half * 32 + j * 8);
            *reinterpret_cast<short8*>(ctxb + gbase + j * 8) = vvv;
        }
    }
    if (lane < 32)
        Lrow[(size_t)bh * S_ + qrow0 + lane] = l_run;
#undef STAGE_LOAD
#undef STAGE_WRITE
}

// ---------------------------------------------------------------------------
// pass 2 (v8, r12 form): Q AND K LDS-staged (coalesced, dbuf, XOR swizzle).
// ---------------------------------------------------------------------------
__global__ __launch_bounds__(256) void k_weights(
    const short* __restrict__ Qh, const short* __restrict__ Kh,
    const float* __restrict__ Lrow,
    float* __restrict__ outw) {
    __shared__ short Kt[2][64 * 64];         // 8 KB each
    __shared__ short Qt[2][128 * 64];        // 16 KB each
    __shared__ float c_lds[1024];            // 4 KB  [h][128 q]
    int tid = threadIdx.x, lane = tid & 63, wv = tid >> 6;
    int l31 = lane & 31, hi = lane >> 5;
    int gid = blockIdx.x;
    int kc = gid & 63, qt = (gid >> 6) & 31, b = gid >> 11;
    int k0 = kc * 64;
    int qblk = qt * 128;
    int qrow0 = qblk + wv * 32;

    {
        int e0 = tid * 4;                    // 0..1023
        int hh = e0 >> 7, qq = e0 & 127;
        size_t base = ((size_t)(b * H_ + hh)) * S_ + qblk + qq;
        f32x4 lv = *reinterpret_cast<const f32x4*>(&Lrow[base]);
        f32x4 cc;
#pragma unroll
        for (int j = 0; j < 4; j++) cc[j] = -3.0f - __log2f(lv[j]);
        *reinterpret_cast<f32x4*>(&c_lds[e0]) = cc;
    }

    int srow8 = lane >> 3;                   // 0..7 (== staged row & 7)
    int scol  = (lane & 7) * 8;              // source col, shorts
    int swz   = (scol * 2) ^ (srow8 << 4);   // swizzled dest byte col

    const short* Kbase = Kh + ((size_t)(b * H_) * S_ + k0) * D_;     // + h*S*D
    const short* Qbase = Qh + ((size_t)(b * H_) * S_ + qblk) * D_;   // + h*S*D

    short8 kst[2], qst[4];
#pragma unroll
    for (int ci = 0; ci < 2; ci++)
        kst[ci] = *reinterpret_cast<const short8*>(
            Kbase + (size_t)(wv * 16 + ci * 8 + srow8) * D_ + scol);
#pragma unroll
    for (int ci = 0; ci < 4; ci++)
        qst[ci] = *reinterpret_cast<const short8*>(
            Qbase + (size_t)(wv * 32 + ci * 8 + srow8) * D_ + scol);
#pragma unroll
    for (int ci = 0; ci < 2; ci++)
        *reinterpret_cast<short8*>((char*)Kt[0] + (wv * 16 + ci * 8 + srow8) * 128 + swz) = kst[ci];
#pragma unroll
    for (int ci = 0; ci < 4; ci++)
        *reinterpret_cast<short8*>((char*)Qt[0] + (wv * 32 + ci * 8 + srow8) * 128 + swz) = qst[ci];
    __syncthreads();

    f32x16 w0, w1;
#pragma unroll
    for (int r = 0; r < 16; r++) { w0[r] = 0.f; w1[r] = 0.f; }

    int cur = 0;
    for (int h = 0; h < H_; ++h) {
        if (h < 7) {   // T14: issue next head's staging loads early (coalesced)
            const short* kp = Kbase + (size_t)(h + 1) * S_ * D_;
            const short* qp = Qbase + (size_t)(h + 1) * S_ * D_;
#pragma unroll
            for (int ci = 0; ci < 2; ci++)
                kst[ci] = *reinterpret_cast<const short8*>(
                    kp + (size_t)(wv * 16 + ci * 8 + srow8) * D_ + scol);
#pragma unroll
            for (int ci = 0; ci < 4; ci++)
                qst[ci] = *reinterpret_cast<const short8*>(
                    qp + (size_t)(wv * 32 + ci * 8 + srow8) * D_ + scol);
        }
        f32x16 s0, s1;
#pragma unroll
        for (int g = 0; g < 4; g++) {
            f32x4 ci4 = *reinterpret_cast<const f32x4*>(
                &c_lds[h * 128 + wv * 32 + 4 * hi + 8 * g]);
#pragma unroll
            for (int j = 0; j < 4; j++) { s0[g * 4 + j] = ci4[j]; s1[g * 4 + j] = ci4[j]; }
        }
#pragma unroll
        for (int ks = 0; ks < 4; ks++) {
            short8 aq = lds_rd(Qt[cur], wv * 32 + l31, ks * 32 + hi * 16);
            short8 b0 = lds_rd(Kt[cur], l31,           ks * 32 + hi * 16);
            short8 b1 = lds_rd(Kt[cur], 32 + l31,      ks * 32 + hi * 16);
            s0 = __builtin_amdgcn_mfma_f32_32x32x16_bf16(aq, b0, s0, 0, 0, 0);
            s1 = __builtin_amdgcn_mfma_f32_32x32x16_bf16(aq, b1, s1, 0, 0, 0);
        }
#pragma unroll
        for (int r = 0; r < 16; r++) {
            w0[r] += __builtin_amdgcn_exp2f(s0[r]);
            w1[r] += __builtin_amdgcn_exp2f(s1[r]);
        }
        if (h < 7) {
#pragma unroll
            for (int ci = 0; ci < 2; ci++)
                *reinterpret_cast<short8*>((char*)Kt[cur ^ 1] + (wv * 16 + ci * 8 + srow8) * 128 + swz) = kst[ci];
#pragma unroll
            for (int ci = 0; ci < 4; ci++)
                *reinterpret_cast<short8*>((char*)Qt[cur ^ 1] + (wv * 32 + ci * 8 + srow8) * 128 + swz) = qst[ci];
        }
        __syncthreads();
        cur ^= 1;
    }
#pragma unroll
    for (int r = 0; r < 16; r++) {
        int qrow = qrow0 + (r & 3) + 8 * (r >> 2) + 4 * hi;
        float* op = outw + ((size_t)b * S_ + qrow) * (size_t)S_ + k0;
        op[l31]      = w0[r];
        op[32 + l31] = w1[r];
    }
}

// ---------------------------------------------------------------------------
extern "C" void kernel_launch(void* const* d_in, const int* in_sizes, int n_in,
                              void* d_out, int out_size, void* d_ws, size_t ws_size,
                              hipStream_t stream) {
    (void)in_sizes; (void)n_in; (void)out_size; (void)ws_size;
    const float* q     = (const float*)d_in[0];
    const float* k     = (const float*)d_in[1];
    const float* v     = (const float*)d_in[2];
    const float* in_w  = (const float*)d_in[3];
    const float* in_b  = (const float*)d_in[4];
    const float* out_w = (const float*)d_in[5];
    const float* out_b = (const float*)d_in[6];
    float* out  = (float*)d_out;
    float* outw = out + (size_t)B_ * S_ * E_;

    char* ws = (char*)d_ws;
    size_t off = 0;
    auto alloc = [&](size_t bytes) { void* p = ws + off; off += (bytes + 255) & ~(size_t)255; return p; };

    float2* cs   = (float2*)alloc((size_t)S_ * 256 * 8);          //  8.4 MB
    short*  Aq   = (short*) alloc((size_t)BS_ * E_ * 2);          //  8.4 MB
    short*  Ak   = (short*) alloc((size_t)BS_ * E_ * 2);          //  8.4 MB
    short*  Av   = (short*) alloc((size_t)BS_ * E_ * 2);          //  8.4 MB
    short*  Wall = (short*) alloc((size_t)3 * E_ * E_ * 2);       //  1.6 MB (Wq|Wk|Wv)
    short*  Wo   = (short*) alloc((size_t)E_ * E_ * 2);           //  0.5 MB
    short*  Qh   = (short*) alloc((size_t)B_ * H_ * S_ * D_ * 2); //  8.4 MB
    short*  Kh   = (short*) alloc((size_t)B_ * H_ * S_ * D_ * 2); //  8.4 MB
    short*  Vt   = (short*) alloc((size_t)B_ * H_ * D_ * S_ * 2); //  8.4 MB
    short*  ctxb = (short*) alloc((size_t)BS_ * E_ * 2);          //  8.4 MB
    float*  Lrow = (float*) alloc((size_t)B_ * H_ * S_ * 4);

    k_cstable<<<S_, 256, 0, stream>>>(cs);
    k_rope2<<<dim3(BS_, 2), 256, 0, stream>>>(q, k, cs, Aq, Ak);
    k_cast3<<<(NV8 + NW18 + NW28 + 255) / 256, 256, 0, stream>>>(v, in_w, out_w, Av, Wall, Wo);

    k_gemm_qkv<<<dim3(E_ / 128, BS_ / 128, 3), 256, 0, stream>>>(
        Aq, Ak, Av, Wall, in_b, Qh, Kh, Vt);
    k_flash<<<B_ * H_ * (S_ / 128), 256, 0, stream>>>(Qh, Kh, Vt, ctxb, Lrow);
    k_gemm_out<<<dim3(E_ / 128, BS_ / 128), 256, 0, stream>>>(ctxb, Wo, out_b, out);
    k_weights<<<B_ * (S_ / 128) * (S_ / 64), 256, 0, stream>>>(Qh, Kh, Lrow, outw);
}

// Round 18
// 235.382 us; speedup vs baseline: 1.0235x; 1.0235x over previous
//
#include <hip/hip_runtime.h>
#include <stdint.h>
#include <stddef.h>

// ---------------------------------------------------------------------------
// MultiheadAttentionWithRope  (B=2, S=4096, E=512, H=8, D=64)
// Round 18: revert setprio from k_flash (r17 A/B: +11us regression, matches
// m190 lockstep-null). Keep fused V-transpose (r17's win). 7 dispatches.
// ---------------------------------------------------------------------------

#define B_ 2
#define S_ 4096
#define E_ 512
#define H_ 8
#define D_ 64
#define BS_ (B_*S_)      // 8192

typedef __attribute__((ext_vector_type(8)))  short short8;
typedef __attribute__((ext_vector_type(4)))  float f32x4;
typedef __attribute__((ext_vector_type(16))) float f32x16;
typedef __attribute__((ext_vector_type(4)))  int   i32x4;

#define DEVFN static __device__ __forceinline__

DEVFN short f2bf(float x) {                 // f32 -> bf16 bits, RNE
    unsigned u = __builtin_bit_cast(unsigned, x);
    u += 0x7fffu + ((u >> 16) & 1u);
    return (short)(u >> 16);
}

// ---------------------------------------------------------------------------
// cos/sin table [S][256] float2, computed in double (angle error << f32 ref)
// ---------------------------------------------------------------------------
__global__ void k_cstable(float2* __restrict__ cs) {
    int pos = blockIdx.x;        // 0..4095
    int i   = threadIdx.x;       // 0..255
    double ang = (double)pos * exp(-0.035977892078031968 * (double)i);
    cs[pos * 256 + i] = make_float2((float)cos(ang), (float)sin(ang));
}

// ---------------------------------------------------------------------------
// RoPE both q and k in one dispatch: blockIdx.y selects stream.
// ---------------------------------------------------------------------------
__global__ void k_rope2(const float* __restrict__ q, const float* __restrict__ k,
                        const float2* __restrict__ cs,
                        short* __restrict__ Aq, short* __restrict__ Ak) {
    int row = blockIdx.x;        // 0..8191 (b*S+s)
    int i   = threadIdx.x;       // pair index 0..255
    const float* x   = blockIdx.y ? k  : q;
    short*       out = blockIdx.y ? Ak : Aq;
    int s = row & (S_ - 1);
    float2 c = cs[s * 256 + i];
    float x1 = x[(size_t)row * E_ + 2 * i];
    float x2 = x[(size_t)row * E_ + 2 * i + 1];
    float r1 = x1 * c.x - x2 * c.y;
    float r2 = x1 * c.y + x2 * c.x;
    unsigned pk = ((unsigned)(unsigned short)f2bf(r1)) |
                  (((unsigned)(unsigned short)f2bf(r2)) << 16);
    *reinterpret_cast<unsigned*>(out + (size_t)row * E_ + 2 * i) = pk;
}

// ---------------------------------------------------------------------------
// all three f32->bf16 casts in one segmented dispatch
// ---------------------------------------------------------------------------
#define NV8  (BS_ * E_ / 8)        // 524288
#define NW18 (3 * E_ * E_ / 8)     //  98304
#define NW28 (E_ * E_ / 8)         //  32768
__global__ void k_cast3(const float* __restrict__ v, const float* __restrict__ in_w,
                        const float* __restrict__ out_w,
                        short* __restrict__ Av, short* __restrict__ Wall,
                        short* __restrict__ Wo) {
    int i = blockIdx.x * 256 + threadIdx.x;
    const float* src; short* dst; int j;
    if (i < NV8)               { src = v;     dst = Av;   j = i; }
    else if (i < NV8 + NW18)   { src = in_w;  dst = Wall; j = i - NV8; }
    else if (i < NV8 + NW18 + NW28) { src = out_w; dst = Wo; j = i - NV8 - NW18; }
    else return;
    f32x4 a = *reinterpret_cast<const f32x4*>(src + (size_t)j * 8);
    f32x4 b = *reinterpret_cast<const f32x4*>(src + (size_t)j * 8 + 4);
    short8 o;
#pragma unroll
    for (int t = 0; t < 4; t++) { o[t] = f2bf(a[t]); o[4 + t] = f2bf(b[t]); }
    *reinterpret_cast<short8*>(dst + (size_t)j * 8) = o;
}

// ---------------------------------------------------------------------------
// Batched QKV projection GEMM: one dispatch, blockIdx.z in {0,1,2}.
// z=0: Qh [b,h,s,64] (0.125*log2e scale); z=1: Kh [b,h,s,64];
// z=2: Vt [b,h,d,s] DIRECTLY (transpose via dead staging LDS in epilogue).
// ---------------------------------------------------------------------------
__global__ __launch_bounds__(256) void k_gemm_qkv(
    const short* __restrict__ Aq, const short* __restrict__ Ak,
    const short* __restrict__ Av, const short* __restrict__ Wall,
    const float* __restrict__ in_b,
    short* __restrict__ Qh, short* __restrict__ Kh, short* __restrict__ Vt) {
    __shared__ short smem2[2][128 * 72];   // sA / sB; reused as 128x144 tr tile
    short* sA = smem2[0];
    short* sB = smem2[1];
    int z = blockIdx.z;
    const short* A  = (z == 0) ? Aq : (z == 1) ? Ak : Av;
    const short* Bw = Wall + (size_t)z * E_ * E_;
    const float* bias = in_b + z * E_;
    int tid = threadIdx.x;
    int lane = tid & 63, wv = tid >> 6;
    int lane16 = lane & 15, lgrp = lane >> 4;
    int row0 = blockIdx.y * 128;
    int col0 = blockIdx.x * 128;
    int wr = (wv >> 1) * 64, wc = (wv & 1) * 64;

    f32x4 acc[4][4];
#pragma unroll
    for (int i = 0; i < 4; i++)
#pragma unroll
        for (int j = 0; j < 4; j++)
#pragma unroll
            for (int r = 0; r < 4; r++) acc[i][j][r] = 0.f;

    for (int kt = 0; kt < 8; ++kt) {
        short8 va[4], vb[4];
#pragma unroll
        for (int i = 0; i < 4; i++) {
            int ch = i * 256 + tid;
            int r = ch >> 3, ce = (ch & 7) * 8;
            va[i] = *reinterpret_cast<const short8*>(A  + (size_t)(row0 + r) * E_ + kt * 64 + ce);
            vb[i] = *reinterpret_cast<const short8*>(Bw + (size_t)(col0 + r) * E_ + kt * 64 + ce);
        }
        __syncthreads();
#pragma unroll
        for (int i = 0; i < 4; i++) {
            int ch = i * 256 + tid;
            int r = ch >> 3, ce = (ch & 7) * 8;
            *reinterpret_cast<short8*>(sA + r * 72 + ce) = va[i];
            *reinterpret_cast<short8*>(sB + r * 72 + ce) = vb[i];
        }
        __syncthreads();
#pragma unroll
        for (int ks = 0; ks < 2; ++ks) {
            short8 af[4];
#pragma unroll
            for (int i = 0; i < 4; i++)
                af[i] = *reinterpret_cast<const short8*>(sA + (wr + i * 16 + lane16) * 72 + ks * 32 + lgrp * 8);
#pragma unroll
            for (int j = 0; j < 4; j++) {
                short8 bf = *reinterpret_cast<const short8*>(sB + (wc + j * 16 + lane16) * 72 + ks * 32 + lgrp * 8);
#pragma unroll
                for (int i = 0; i < 4; i++)
                    acc[i][j] = __builtin_amdgcn_mfma_f32_16x16x32_bf16(af[i], bf, acc[i][j], 0, 0, 0);
            }
        }
    }
    if (z == 2) {
        // ---- transpose epilogue: C^T through LDS, coalesced Vt[d][s] stores
        __syncthreads();                       // staging buffers now dead
        short* tr = &smem2[0][0];              // 128 x 144 (stride pad)
#pragma unroll
        for (int i = 0; i < 4; i++) {
#pragma unroll
            for (int j = 0; j < 4; j++) {
                int cl = wc + j * 16 + lane16;
                float bv = bias[col0 + cl];
#pragma unroll
                for (int r = 0; r < 4; r++) {
                    int rl = wr + i * 16 + lgrp * 4 + r;
                    tr[cl * 144 + rl] = f2bf(acc[i][j][r] + bv);
                }
            }
        }
        __syncthreads();
        {
            int el = tid >> 1, shalf = (tid & 1) * 64;     // e-row, s-half
            int colg = col0 + el;
            int h = colg >> 6, d = colg & 63;
            int b = row0 >> 12, s0 = row0 & (S_ - 1);
            size_t dst = ((size_t)(b * H_ + h) * D_ + d) * S_ + s0 + shalf;
#pragma unroll
            for (int jj = 0; jj < 8; jj++) {
                short8 vv = *reinterpret_cast<const short8*>(tr + el * 144 + shalf + jj * 8);
                *reinterpret_cast<short8*>(Vt + dst + jj * 8) = vv;
            }
        }
        return;
    }
#pragma unroll
    for (int i = 0; i < 4; i++) {
#pragma unroll
        for (int j = 0; j < 4; j++) {
            int col = col0 + wc + j * 16 + lane16;
            float bv = bias[col];
#pragma unroll
            for (int r = 0; r < 4; r++) {
                int row = row0 + wr + i * 16 + lgrp * 4 + r;
                float vx = acc[i][j][r] + bv;
                int b = row >> 12, s = row & (S_ - 1);
                int h = col >> 6, d = col & 63;
                if (z == 0) {
                    vx *= 0.18033688011112042f;   // 0.125 * log2(e)
                    Qh[((size_t)(b * H_ + h) * S_ + s) * D_ + d] = f2bf(vx);
                } else {
                    Kh[((size_t)(b * H_ + h) * S_ + s) * D_ + d] = f2bf(vx);
                }
            }
        }
    }
}

// ---------------------------------------------------------------------------
// out-proj GEMM (f32 out)
// ---------------------------------------------------------------------------
__global__ __launch_bounds__(256) void k_gemm_out(
    const short* __restrict__ A, const short* __restrict__ Bw,
    const float* __restrict__ bias, float* __restrict__ out_f) {
    __shared__ short sA[128 * 72];
    __shared__ short sB[128 * 72];
    int tid = threadIdx.x;
    int lane = tid & 63, wv = tid >> 6;
    int lane16 = lane & 15, lgrp = lane >> 4;
    int row0 = blockIdx.y * 128;
    int col0 = blockIdx.x * 128;
    int wr = (wv >> 1) * 64, wc = (wv & 1) * 64;

    f32x4 acc[4][4];
#pragma unroll
    for (int i = 0; i < 4; i++)
#pragma unroll
        for (int j = 0; j < 4; j++)
#pragma unroll
            for (int r = 0; r < 4; r++) acc[i][j][r] = 0.f;

    for (int kt = 0; kt < 8; ++kt) {
        short8 va[4], vb[4];
#pragma unroll
        for (int i = 0; i < 4; i++) {
            int ch = i * 256 + tid;
            int r = ch >> 3, ce = (ch & 7) * 8;
            va[i] = *reinterpret_cast<const short8*>(A  + (size_t)(row0 + r) * E_ + kt * 64 + ce);
            vb[i] = *reinterpret_cast<const short8*>(Bw + (size_t)(col0 + r) * E_ + kt * 64 + ce);
        }
        __syncthreads();
#pragma unroll
        for (int i = 0; i < 4; i++) {
            int ch = i * 256 + tid;
            int r = ch >> 3, ce = (ch & 7) * 8;
            *reinterpret_cast<short8*>(sA + r * 72 + ce) = va[i];
            *reinterpret_cast<short8*>(sB + r * 72 + ce) = vb[i];
        }
        __syncthreads();
#pragma unroll
        for (int ks = 0; ks < 2; ++ks) {
            short8 af[4];
#pragma unroll
            for (int i = 0; i < 4; i++)
                af[i] = *reinterpret_cast<const short8*>(sA + (wr + i * 16 + lane16) * 72 + ks * 32 + lgrp * 8);
#pragma unroll
            for (int j = 0; j < 4; j++) {
                short8 bf = *reinterpret_cast<const short8*>(sB + (wc + j * 16 + lane16) * 72 + ks * 32 + lgrp * 8);
#pragma unroll
                for (int i = 0; i < 4; i++)
                    acc[i][j] = __builtin_amdgcn_mfma_f32_16x16x32_bf16(af[i], bf, acc[i][j], 0, 0, 0);
            }
        }
    }
#pragma unroll
    for (int i = 0; i < 4; i++) {
#pragma unroll
        for (int j = 0; j < 4; j++) {
            int col = col0 + wc + j * 16 + lane16;
            float bv = bias[col];
#pragma unroll
            for (int r = 0; r < 4; r++) {
                int row = row0 + wr + i * 16 + lgrp * 4 + r;
                out_f[(size_t)row * E_ + col] = acc[i][j][r] + bv;
            }
        }
    }
}

// ---------------------------------------------------------------------------
// flash (r12 form, no setprio): fixed-max, reg-staged dbuf LDS.
// ---------------------------------------------------------------------------
DEVFN short8 lds_rd(const short* buf, int row, int colb) {
    return *reinterpret_cast<const short8*>(
        (const char*)buf + row * 128 + (colb ^ ((row & 7) << 4)));
}

__global__ __launch_bounds__(256) void k_flash(
    const short* __restrict__ Qh, const short* __restrict__ Kh,
    const short* __restrict__ Vt, short* __restrict__ ctxb,
    float* __restrict__ Lrow) {
    __shared__ short kbuf[2][64 * 64];     // 16 KB
    __shared__ short vbuf[2][64 * 64];     // 16 KB
    __shared__ short ob[4][32 * 72];       // 18 KB epilogue transpose
    int tid = threadIdx.x, lane = tid & 63, wv = tid >> 6;
    int l31 = lane & 31, hi = lane >> 5;
    int gid = blockIdx.x;
    int qt = gid & 31, h = (gid >> 5) & 7, b = gid >> 8;
    int bh = b * H_ + h;
    int qrow0 = qt * 128 + wv * 32;
    const short* Qp = Qh + ((size_t)bh * S_ + qrow0) * D_;
    const short* Kp = Kh + (size_t)bh * S_ * D_;
    const short* Vp = Vt + (size_t)bh * 64 * S_;

    short8 qf[4];
#pragma unroll
    for (int ds = 0; ds < 4; ds++)
        qf[ds] = *reinterpret_cast<const short8*>(
            Qp + (size_t)l31 * D_ + ds * 16 + hi * 8);

    f32x16 ctx0, ctx1;
#pragma unroll
    for (int r = 0; r < 16; r++) { ctx0[r] = 0.f; ctx1[r] = 0.f; }
    float lsum = 0.f;

    int srow = wv * 16 + (lane >> 3);            // +ci*8
    int scol = (lane & 7) * 8;                   // shorts
    int swz  = (scol * 2) ^ ((lane >> 3) << 4);  // swizzled byte col

    short8 kst[2], vst[2];
#define STAGE_LOAD(kb_) do {                                                     \
    int nb_ = (kb_);                                                             \
    _Pragma("unroll") for (int ci = 0; ci < 2; ci++) {                           \
        int r_ = srow + ci * 8;                                                  \
        kst[ci] = *reinterpret_cast<const short8*>(Kp + (size_t)(nb_ + r_) * D_ + scol); \
        vst[ci] = *reinterpret_cast<const short8*>(Vp + (size_t)r_ * S_ + nb_ + scol);   \
    } } while (0)
#define STAGE_WRITE(d_) do {                                                     \
    _Pragma("unroll") for (int ci = 0; ci < 2; ci++) {                           \
        int r_ = srow + ci * 8;                                                  \
        *reinterpret_cast<short8*>((char*)kbuf[d_] + r_ * 128 + swz) = kst[ci];  \
        *reinterpret_cast<short8*>((char*)vbuf[d_] + r_ * 128 + swz) = vst[ci];  \
    } } while (0)

    STAGE_LOAD(0);
    STAGE_WRITE(0);
    __syncthreads();
    int cur = 0;

    for (int kt = 0; kt < 64; ++kt) {
        if (kt < 63) STAGE_LOAD((kt + 1) * 64);   // T14: issue early

        f32x16 s0, s1;
#pragma unroll
        for (int r = 0; r < 16; r++) { s0[r] = 0.f; s1[r] = 0.f; }
#pragma unroll
        for (int ds = 0; ds < 4; ds++) {
            short8 k0 = lds_rd(kbuf[cur], l31,      ds * 32 + hi * 16);
            short8 k1 = lds_rd(kbuf[cur], 32 + l31, ds * 32 + hi * 16);
            s0 = __builtin_amdgcn_mfma_f32_32x32x16_bf16(k0, qf[ds], s0, 0, 0, 0);
            s1 = __builtin_amdgcn_mfma_f32_32x32x16_bf16(k1, qf[ds], s1, 0, 0, 0);
        }
#pragma unroll
        for (int r = 0; r < 16; r++) { s0[r] = __builtin_amdgcn_exp2f(s0[r]); lsum += s0[r]; }
#pragma unroll
        for (int r = 0; r < 16; r++) { s1[r] = __builtin_amdgcn_exp2f(s1[r]); lsum += s1[r]; }

        int w[16];
#pragma unroll
        for (int t = 0; t < 8; t++) {
            asm("v_cvt_pk_bf16_f32 %0, %1, %2" : "=v"(w[t])     : "v"(s0[2 * t]), "v"(s0[2 * t + 1]));
            asm("v_cvt_pk_bf16_f32 %0, %1, %2" : "=v"(w[8 + t]) : "v"(s1[2 * t]), "v"(s1[2 * t + 1]));
        }
        short8 pf[4];
#pragma unroll
        for (int g = 0; g < 4; g++) {
            int a0 = w[g * 4 + 0], b0 = w[g * 4 + 2];
            int a1 = w[g * 4 + 1], b1 = w[g * 4 + 3];
            asm("v_permlane32_swap_b32 %0, %1" : "+v"(a0), "+v"(b0));
            asm("v_permlane32_swap_b32 %0, %1" : "+v"(a1), "+v"(b1));
            i32x4 t4 = {a0, a1, b0, b1};
            pf[g] = __builtin_bit_cast(short8, t4);
        }
#pragma unroll
        for (int ks = 0; ks < 4; ks++) {
            short8 v0 = lds_rd(vbuf[cur], l31,      ks * 32 + hi * 16);
            short8 v1 = lds_rd(vbuf[cur], 32 + l31, ks * 32 + hi * 16);
            ctx0 = __builtin_amdgcn_mfma_f32_32x32x16_bf16(v0, pf[ks], ctx0, 0, 0, 0);
            ctx1 = __builtin_amdgcn_mfma_f32_32x32x16_bf16(v1, pf[ks], ctx1, 0, 0, 0);
        }
        if (kt < 63) STAGE_WRITE(cur ^ 1);        // T14: write late
        __syncthreads();
        cur ^= 1;
    }

    float l_run = lsum + __shfl_xor(lsum, 32);
    float invl = 1.0f / l_run;
    short* obw = &ob[wv][0];
#pragma unroll
    for (int n = 0; n < 2; n++) {
#pragma unroll
        for (int t = 0; t < 8; t++) {
            float a  = (n ? ctx1[2 * t]     : ctx0[2 * t])     * invl;
            float bb = (n ? ctx1[2 * t + 1] : ctx0[2 * t + 1]) * invl;
            int wd;
            asm("v_cvt_pk_bf16_f32 %0, %1, %2" : "=v"(wd) : "v"(a), "v"(bb));
            int d = n * 32 + ((2 * t) & 3) + 8 * ((2 * t) >> 2) + 4 * hi;
            *reinterpret_cast<int*>(obw + l31 * 72 + d) = wd;
        }
    }
    __syncthreads();
    {
        int q = lane >> 1, half = lane & 1;
        size_t gbase = ((size_t)b * S_ + qrow0 + q) * E_ + h * 64 + half * 32;
#pragma unroll
        for (int j = 0; j < 4; j++) {
            short8 vvv = *reinterpret_cast<const short8*>(obw + q * 72 + half * 32 + j * 8);
            *reinterpret_cast<short8*>(ctxb + gbase + j * 8) = vvv;
        }
    }
    if (lane < 32)
        Lrow[(size_t)bh * S_ + qrow0 + lane] = l_run;
#undef STAGE_LOAD
#undef STAGE_WRITE
}

// ---------------------------------------------------------------------------
// pass 2 (v8, r12 form): Q AND K LDS-staged (coalesced, dbuf, XOR swizzle).
// ---------------------------------------------------------------------------
__global__ __launch_bounds__(256) void k_weights(
    const short* __restrict__ Qh, const short* __restrict__ Kh,
    const float* __restrict__ Lrow,
    float* __restrict__ outw) {
    __shared__ short Kt[2][64 * 64];         // 8 KB each
    __shared__ short Qt[2][128 * 64];        // 16 KB each
    __shared__ float c_lds[1024];            // 4 KB  [h][128 q]
    int tid = threadIdx.x, lane = tid & 63, wv = tid >> 6;
    int l31 = lane & 31, hi = lane >> 5;
    int gid = blockIdx.x;
    int kc = gid & 63, qt = (gid >> 6) & 31, b = gid >> 11;
    int k0 = kc * 64;
    int qblk = qt * 128;
    int qrow0 = qblk + wv * 32;

    {
        int e0 = tid * 4;                    // 0..1023
        int hh = e0 >> 7, qq = e0 & 127;
        size_t base = ((size_t)(b * H_ + hh)) * S_ + qblk + qq;
        f32x4 lv = *reinterpret_cast<const f32x4*>(&Lrow[base]);
        f32x4 cc;
#pragma unroll
        for (int j = 0; j < 4; j++) cc[j] = -3.0f - __log2f(lv[j]);
        *reinterpret_cast<f32x4*>(&c_lds[e0]) = cc;
    }

    int srow8 = lane >> 3;                   // 0..7 (== staged row & 7)
    int scol  = (lane & 7) * 8;              // source col, shorts
    int swz   = (scol * 2) ^ (srow8 << 4);   // swizzled dest byte col

    const short* Kbase = Kh + ((size_t)(b * H_) * S_ + k0) * D_;     // + h*S*D
    const short* Qbase = Qh + ((size_t)(b * H_) * S_ + qblk) * D_;   // + h*S*D

    short8 kst[2], qst[4];
#pragma unroll
    for (int ci = 0; ci < 2; ci++)
        kst[ci] = *reinterpret_cast<const short8*>(
            Kbase + (size_t)(wv * 16 + ci * 8 + srow8) * D_ + scol);
#pragma unroll
    for (int ci = 0; ci < 4; ci++)
        qst[ci] = *reinterpret_cast<const short8*>(
            Qbase + (size_t)(wv * 32 + ci * 8 + srow8) * D_ + scol);
#pragma unroll
    for (int ci = 0; ci < 2; ci++)
        *reinterpret_cast<short8*>((char*)Kt[0] + (wv * 16 + ci * 8 + srow8) * 128 + swz) = kst[ci];
#pragma unroll
    for (int ci = 0; ci < 4; ci++)
        *reinterpret_cast<short8*>((char*)Qt[0] + (wv * 32 + ci * 8 + srow8) * 128 + swz) = qst[ci];
    __syncthreads();

    f32x16 w0, w1;
#pragma unroll
    for (int r = 0; r < 16; r++) { w0[r] = 0.f; w1[r] = 0.f; }

    int cur = 0;
    for (int h = 0; h < H_; ++h) {
        if (h < 7) {   // T14: issue next head's staging loads early (coalesced)
            const short* kp = Kbase + (size_t)(h + 1) * S_ * D_;
            const short* qp = Qbase + (size_t)(h + 1) * S_ * D_;
#pragma unroll
            for (int ci = 0; ci < 2; ci++)
                kst[ci] = *reinterpret_cast<const short8*>(
                    kp + (size_t)(wv * 16 + ci * 8 + srow8) * D_ + scol);
#pragma unroll
            for (int ci = 0; ci < 4; ci++)
                qst[ci] = *reinterpret_cast<const short8*>(
                    qp + (size_t)(wv * 32 + ci * 8 + srow8) * D_ + scol);
        }
        f32x16 s0, s1;
#pragma unroll
        for (int g = 0; g < 4; g++) {
            f32x4 ci4 = *reinterpret_cast<const f32x4*>(
                &c_lds[h * 128 + wv * 32 + 4 * hi + 8 * g]);
#pragma unroll
            for (int j = 0; j < 4; j++) { s0[g * 4 + j] = ci4[j]; s1[g * 4 + j] = ci4[j]; }
        }
#pragma unroll
        for (int ks = 0; ks < 4; ks++) {
            short8 aq = lds_rd(Qt[cur], wv * 32 + l31, ks * 32 + hi * 16);
            short8 b0 = lds_rd(Kt[cur], l31,           ks * 32 + hi * 16);
            short8 b1 = lds_rd(Kt[cur], 32 + l31,      ks * 32 + hi * 16);
            s0 = __builtin_amdgcn_mfma_f32_32x32x16_bf16(aq, b0, s0, 0, 0, 0);
            s1 = __builtin_amdgcn_mfma_f32_32x32x16_bf16(aq, b1, s1, 0, 0, 0);
        }
#pragma unroll
        for (int r = 0; r < 16; r++) {
            w0[r] += __builtin_amdgcn_exp2f(s0[r]);
            w1[r] += __builtin_amdgcn_exp2f(s1[r]);
        }
        if (h < 7) {
#pragma unroll
            for (int ci = 0; ci < 2; ci++)
                *reinterpret_cast<short8*>((char*)Kt[cur ^ 1] + (wv * 16 + ci * 8 + srow8) * 128 + swz) = kst[ci];
#pragma unroll
            for (int ci = 0; ci < 4; ci++)
                *reinterpret_cast<short8*>((char*)Qt[cur ^ 1] + (wv * 32 + ci * 8 + srow8) * 128 + swz) = qst[ci];
        }
        __syncthreads();
        cur ^= 1;
    }
#pragma unroll
    for (int r = 0; r < 16; r++) {
        int qrow = qrow0 + (r & 3) + 8 * (r >> 2) + 4 * hi;
        float* op = outw + ((size_t)b * S_ + qrow) * (size_t)S_ + k0;
        op[l31]      = w0[r];
        op[32 + l31] = w1[r];
    }
}

// ---------------------------------------------------------------------------
extern "C" void kernel_launch(void* const* d_in, const int* in_sizes, int n_in,
                              void* d_out, int out_size, void* d_ws, size_t ws_size,
                              hipStream_t stream) {
    (void)in_sizes; (void)n_in; (void)out_size; (void)ws_size;
    const float* q     = (const float*)d_in[0];
    const float* k     = (const float*)d_in[1];
    const float* v     = (const float*)d_in[2];
    const float* in_w  = (const float*)d_in[3];
    const float* in_b  = (const float*)d_in[4];
    const float* out_w = (const float*)d_in[5];
    const float* out_b = (const float*)d_in[6];
    float* out  = (float*)d_out;
    float* outw = out + (size_t)B_ * S_ * E_;

    char* ws = (char*)d_ws;
    size_t off = 0;
    auto alloc = [&](size_t bytes) { void* p = ws + off; off += (bytes + 255) & ~(size_t)255; return p; };

    float2* cs   = (float2*)alloc((size_t)S_ * 256 * 8);          //  8.4 MB
    short*  Aq   = (short*) alloc((size_t)BS_ * E_ * 2);          //  8.4 MB
    short*  Ak   = (short*) alloc((size_t)BS_ * E_ * 2);          //  8.4 MB
    short*  Av   = (short*) alloc((size_t)BS_ * E_ * 2);          //  8.4 MB
    short*  Wall = (short*) alloc((size_t)3 * E_ * E_ * 2);       //  1.6 MB (Wq|Wk|Wv)
    short*  Wo   = (short*) alloc((size_t)E_ * E_ * 2);           //  0.5 MB
    short*  Qh   = (short*) alloc((size_t)B_ * H_ * S_ * D_ * 2); //  8.4 MB
    short*  Kh   = (short*) alloc((size_t)B_ * H_ * S_ * D_ * 2); //  8.4 MB
    short*  Vt   = (short*) alloc((size_t)B_ * H_ * D_ * S_ * 2); //  8.4 MB
    short*  ctxb = (short*) alloc((size_t)BS_ * E_ * 2);          //  8.4 MB
    float*  Lrow = (float*) alloc((size_t)B_ * H_ * S_ * 4);

    k_cstable<<<S_, 256, 0, stream>>>(cs);
    k_rope2<<<dim3(BS_, 2), 256, 0, stream>>>(q, k, cs, Aq, Ak);
    k_cast3<<<(NV8 + NW18 + NW28 + 255) / 256, 256, 0, stream>>>(v, in_w, out_w, Av, Wall, Wo);

    k_gemm_qkv<<<dim3(E_ / 128, BS_ / 128, 3), 256, 0, stream>>>(
        Aq, Ak, Av, Wall, in_b, Qh, Kh, Vt);
    k_flash<<<B_ * H_ * (S_ / 128), 256, 0, stream>>>(Qh, Kh, Vt, ctxb, Lrow);
    k_gemm_out<<<dim3(E_ / 128, BS_ / 128), 256, 0, stream>>>(ctxb, Wo, out_b, out);
    k_weights<<<B_ * (S_ / 128) * (S_ / 64), 256, 0, stream>>>(Qh, Kh, Lrow, outw);
}

// Round 19
// 235.160 us; speedup vs baseline: 1.0244x; 1.0009x over previous
//
#include <hip/hip_runtime.h>
#include <stdint.h>
#include <stddef.h>

// ---------------------------------------------------------------------------
// MultiheadAttentionWithRope  (B=2, S=4096, E=512, H=8, D=64)
// Round 19: flash lsum split into 4 independent accumulators (breaks the
// 32-deep serial FP-add chain per k-tile; compiler can't reassociate FP).
// Everything else identical to round 18 (235.4us best).
// ---------------------------------------------------------------------------

#define B_ 2
#define S_ 4096
#define E_ 512
#define H_ 8
#define D_ 64
#define BS_ (B_*S_)      // 8192

typedef __attribute__((ext_vector_type(8)))  short short8;
typedef __attribute__((ext_vector_type(4)))  float f32x4;
typedef __attribute__((ext_vector_type(16))) float f32x16;
typedef __attribute__((ext_vector_type(4)))  int   i32x4;

#define DEVFN static __device__ __forceinline__

DEVFN short f2bf(float x) {                 // f32 -> bf16 bits, RNE
    unsigned u = __builtin_bit_cast(unsigned, x);
    u += 0x7fffu + ((u >> 16) & 1u);
    return (short)(u >> 16);
}

// ---------------------------------------------------------------------------
// cos/sin table [S][256] float2, computed in double (angle error << f32 ref)
// ---------------------------------------------------------------------------
__global__ void k_cstable(float2* __restrict__ cs) {
    int pos = blockIdx.x;        // 0..4095
    int i   = threadIdx.x;       // 0..255
    double ang = (double)pos * exp(-0.035977892078031968 * (double)i);
    cs[pos * 256 + i] = make_float2((float)cos(ang), (float)sin(ang));
}

// ---------------------------------------------------------------------------
// RoPE both q and k in one dispatch: blockIdx.y selects stream.
// ---------------------------------------------------------------------------
__global__ void k_rope2(const float* __restrict__ q, const float* __restrict__ k,
                        const float2* __restrict__ cs,
                        short* __restrict__ Aq, short* __restrict__ Ak) {
    int row = blockIdx.x;        // 0..8191 (b*S+s)
    int i   = threadIdx.x;       // pair index 0..255
    const float* x   = blockIdx.y ? k  : q;
    short*       out = blockIdx.y ? Ak : Aq;
    int s = row & (S_ - 1);
    float2 c = cs[s * 256 + i];
    float x1 = x[(size_t)row * E_ + 2 * i];
    float x2 = x[(size_t)row * E_ + 2 * i + 1];
    float r1 = x1 * c.x - x2 * c.y;
    float r2 = x1 * c.y + x2 * c.x;
    unsigned pk = ((unsigned)(unsigned short)f2bf(r1)) |
                  (((unsigned)(unsigned short)f2bf(r2)) << 16);
    *reinterpret_cast<unsigned*>(out + (size_t)row * E_ + 2 * i) = pk;
}

// ---------------------------------------------------------------------------
// all three f32->bf16 casts in one segmented dispatch
// ---------------------------------------------------------------------------
#define NV8  (BS_ * E_ / 8)        // 524288
#define NW18 (3 * E_ * E_ / 8)     //  98304
#define NW28 (E_ * E_ / 8)         //  32768
__global__ void k_cast3(const float* __restrict__ v, const float* __restrict__ in_w,
                        const float* __restrict__ out_w,
                        short* __restrict__ Av, short* __restrict__ Wall,
                        short* __restrict__ Wo) {
    int i = blockIdx.x * 256 + threadIdx.x;
    const float* src; short* dst; int j;
    if (i < NV8)               { src = v;     dst = Av;   j = i; }
    else if (i < NV8 + NW18)   { src = in_w;  dst = Wall; j = i - NV8; }
    else if (i < NV8 + NW18 + NW28) { src = out_w; dst = Wo; j = i - NV8 - NW18; }
    else return;
    f32x4 a = *reinterpret_cast<const f32x4*>(src + (size_t)j * 8);
    f32x4 b = *reinterpret_cast<const f32x4*>(src + (size_t)j * 8 + 4);
    short8 o;
#pragma unroll
    for (int t = 0; t < 4; t++) { o[t] = f2bf(a[t]); o[4 + t] = f2bf(b[t]); }
    *reinterpret_cast<short8*>(dst + (size_t)j * 8) = o;
}

// ---------------------------------------------------------------------------
// Batched QKV projection GEMM: one dispatch, blockIdx.z in {0,1,2}.
// z=0: Qh [b,h,s,64] (0.125*log2e scale); z=1: Kh [b,h,s,64];
// z=2: Vt [b,h,d,s] DIRECTLY (transpose via dead staging LDS in epilogue).
// ---------------------------------------------------------------------------
__global__ __launch_bounds__(256) void k_gemm_qkv(
    const short* __restrict__ Aq, const short* __restrict__ Ak,
    const short* __restrict__ Av, const short* __restrict__ Wall,
    const float* __restrict__ in_b,
    short* __restrict__ Qh, short* __restrict__ Kh, short* __restrict__ Vt) {
    __shared__ short smem2[2][128 * 72];   // sA / sB; reused as 128x144 tr tile
    short* sA = smem2[0];
    short* sB = smem2[1];
    int z = blockIdx.z;
    const short* A  = (z == 0) ? Aq : (z == 1) ? Ak : Av;
    const short* Bw = Wall + (size_t)z * E_ * E_;
    const float* bias = in_b + z * E_;
    int tid = threadIdx.x;
    int lane = tid & 63, wv = tid >> 6;
    int lane16 = lane & 15, lgrp = lane >> 4;
    int row0 = blockIdx.y * 128;
    int col0 = blockIdx.x * 128;
    int wr = (wv >> 1) * 64, wc = (wv & 1) * 64;

    f32x4 acc[4][4];
#pragma unroll
    for (int i = 0; i < 4; i++)
#pragma unroll
        for (int j = 0; j < 4; j++)
#pragma unroll
            for (int r = 0; r < 4; r++) acc[i][j][r] = 0.f;

    for (int kt = 0; kt < 8; ++kt) {
        short8 va[4], vb[4];
#pragma unroll
        for (int i = 0; i < 4; i++) {
            int ch = i * 256 + tid;
            int r = ch >> 3, ce = (ch & 7) * 8;
            va[i] = *reinterpret_cast<const short8*>(A  + (size_t)(row0 + r) * E_ + kt * 64 + ce);
            vb[i] = *reinterpret_cast<const short8*>(Bw + (size_t)(col0 + r) * E_ + kt * 64 + ce);
        }
        __syncthreads();
#pragma unroll
        for (int i = 0; i < 4; i++) {
            int ch = i * 256 + tid;
            int r = ch >> 3, ce = (ch & 7) * 8;
            *reinterpret_cast<short8*>(sA + r * 72 + ce) = va[i];
            *reinterpret_cast<short8*>(sB + r * 72 + ce) = vb[i];
        }
        __syncthreads();
#pragma unroll
        for (int ks = 0; ks < 2; ++ks) {
            short8 af[4];
#pragma unroll
            for (int i = 0; i < 4; i++)
                af[i] = *reinterpret_cast<const short8*>(sA + (wr + i * 16 + lane16) * 72 + ks * 32 + lgrp * 8);
#pragma unroll
            for (int j = 0; j < 4; j++) {
                short8 bf = *reinterpret_cast<const short8*>(sB + (wc + j * 16 + lane16) * 72 + ks * 32 + lgrp * 8);
#pragma unroll
                for (int i = 0; i < 4; i++)
                    acc[i][j] = __builtin_amdgcn_mfma_f32_16x16x32_bf16(af[i], bf, acc[i][j], 0, 0, 0);
            }
        }
    }
    if (z == 2) {
        // ---- transpose epilogue: C^T through LDS, coalesced Vt[d][s] stores
        __syncthreads();                       // staging buffers now dead
        short* tr = &smem2[0][0];              // 128 x 144 (stride pad)
#pragma unroll
        for (int i = 0; i < 4; i++) {
#pragma unroll
            for (int j = 0; j < 4; j++) {
                int cl = wc + j * 16 + lane16;
                float bv = bias[col0 + cl];
#pragma unroll
                for (int r = 0; r < 4; r++) {
                    int rl = wr + i * 16 + lgrp * 4 + r;
                    tr[cl * 144 + rl] = f2bf(acc[i][j][r] + bv);
                }
            }
        }
        __syncthreads();
        {
            int el = tid >> 1, shalf = (tid & 1) * 64;     // e-row, s-half
            int colg = col0 + el;
            int h = colg >> 6, d = colg & 63;
            int b = row0 >> 12, s0 = row0 & (S_ - 1);
            size_t dst = ((size_t)(b * H_ + h) * D_ + d) * S_ + s0 + shalf;
#pragma unroll
            for (int jj = 0; jj < 8; jj++) {
                short8 vv = *reinterpret_cast<const short8*>(tr + el * 144 + shalf + jj * 8);
                *reinterpret_cast<short8*>(Vt + dst + jj * 8) = vv;
            }
        }
        return;
    }
#pragma unroll
    for (int i = 0; i < 4; i++) {
#pragma unroll
        for (int j = 0; j < 4; j++) {
            int col = col0 + wc + j * 16 + lane16;
            float bv = bias[col];
#pragma unroll
            for (int r = 0; r < 4; r++) {
                int row = row0 + wr + i * 16 + lgrp * 4 + r;
                float vx = acc[i][j][r] + bv;
                int b = row >> 12, s = row & (S_ - 1);
                int h = col >> 6, d = col & 63;
                if (z == 0) {
                    vx *= 0.18033688011112042f;   // 0.125 * log2(e)
                    Qh[((size_t)(b * H_ + h) * S_ + s) * D_ + d] = f2bf(vx);
                } else {
                    Kh[((size_t)(b * H_ + h) * S_ + s) * D_ + d] = f2bf(vx);
                }
            }
        }
    }
}

// ---------------------------------------------------------------------------
// out-proj GEMM (f32 out)
// ---------------------------------------------------------------------------
__global__ __launch_bounds__(256) void k_gemm_out(
    const short* __restrict__ A, const short* __restrict__ Bw,
    const float* __restrict__ bias, float* __restrict__ out_f) {
    __shared__ short sA[128 * 72];
    __shared__ short sB[128 * 72];
    int tid = threadIdx.x;
    int lane = tid & 63, wv = tid >> 6;
    int lane16 = lane & 15, lgrp = lane >> 4;
    int row0 = blockIdx.y * 128;
    int col0 = blockIdx.x * 128;
    int wr = (wv >> 1) * 64, wc = (wv & 1) * 64;

    f32x4 acc[4][4];
#pragma unroll
    for (int i = 0; i < 4; i++)
#pragma unroll
        for (int j = 0; j < 4; j++)
#pragma unroll
            for (int r = 0; r < 4; r++) acc[i][j][r] = 0.f;

    for (int kt = 0; kt < 8; ++kt) {
        short8 va[4], vb[4];
#pragma unroll
        for (int i = 0; i < 4; i++) {
            int ch = i * 256 + tid;
            int r = ch >> 3, ce = (ch & 7) * 8;
            va[i] = *reinterpret_cast<const short8*>(A  + (size_t)(row0 + r) * E_ + kt * 64 + ce);
            vb[i] = *reinterpret_cast<const short8*>(Bw + (size_t)(col0 + r) * E_ + kt * 64 + ce);
        }
        __syncthreads();
#pragma unroll
        for (int i = 0; i < 4; i++) {
            int ch = i * 256 + tid;
            int r = ch >> 3, ce = (ch & 7) * 8;
            *reinterpret_cast<short8*>(sA + r * 72 + ce) = va[i];
            *reinterpret_cast<short8*>(sB + r * 72 + ce) = vb[i];
        }
        __syncthreads();
#pragma unroll
        for (int ks = 0; ks < 2; ++ks) {
            short8 af[4];
#pragma unroll
            for (int i = 0; i < 4; i++)
                af[i] = *reinterpret_cast<const short8*>(sA + (wr + i * 16 + lane16) * 72 + ks * 32 + lgrp * 8);
#pragma unroll
            for (int j = 0; j < 4; j++) {
                short8 bf = *reinterpret_cast<const short8*>(sB + (wc + j * 16 + lane16) * 72 + ks * 32 + lgrp * 8);
#pragma unroll
                for (int i = 0; i < 4; i++)
                    acc[i][j] = __builtin_amdgcn_mfma_f32_16x16x32_bf16(af[i], bf, acc[i][j], 0, 0, 0);
            }
        }
    }
#pragma unroll
    for (int i = 0; i < 4; i++) {
#pragma unroll
        for (int j = 0; j < 4; j++) {
            int col = col0 + wc + j * 16 + lane16;
            float bv = bias[col];
#pragma unroll
            for (int r = 0; r < 4; r++) {
                int row = row0 + wr + i * 16 + lgrp * 4 + r;
                out_f[(size_t)row * E_ + col] = acc[i][j][r] + bv;
            }
        }
    }
}

// ---------------------------------------------------------------------------
// flash (r12 form + 4-way lsum): fixed-max, reg-staged dbuf LDS.
// ---------------------------------------------------------------------------
DEVFN short8 lds_rd(const short* buf, int row, int colb) {
    return *reinterpret_cast<const short8*>(
        (const char*)buf + row * 128 + (colb ^ ((row & 7) << 4)));
}

__global__ __launch_bounds__(256) void k_flash(
    const short* __restrict__ Qh, const short* __restrict__ Kh,
    const short* __restrict__ Vt, short* __restrict__ ctxb,
    float* __restrict__ Lrow) {
    __shared__ short kbuf[2][64 * 64];     // 16 KB
    __shared__ short vbuf[2][64 * 64];     // 16 KB
    __shared__ short ob[4][32 * 72];       // 18 KB epilogue transpose
    int tid = threadIdx.x, lane = tid & 63, wv = tid >> 6;
    int l31 = lane & 31, hi = lane >> 5;
    int gid = blockIdx.x;
    int qt = gid & 31, h = (gid >> 5) & 7, b = gid >> 8;
    int bh = b * H_ + h;
    int qrow0 = qt * 128 + wv * 32;
    const short* Qp = Qh + ((size_t)bh * S_ + qrow0) * D_;
    const short* Kp = Kh + (size_t)bh * S_ * D_;
    const short* Vp = Vt + (size_t)bh * 64 * S_;

    short8 qf[4];
#pragma unroll
    for (int ds = 0; ds < 4; ds++)
        qf[ds] = *reinterpret_cast<const short8*>(
            Qp + (size_t)l31 * D_ + ds * 16 + hi * 8);

    f32x16 ctx0, ctx1;
#pragma unroll
    for (int r = 0; r < 16; r++) { ctx0[r] = 0.f; ctx1[r] = 0.f; }
    float lacc[4] = {0.f, 0.f, 0.f, 0.f};    // 4 independent partial sums

    int srow = wv * 16 + (lane >> 3);            // +ci*8
    int scol = (lane & 7) * 8;                   // shorts
    int swz  = (scol * 2) ^ ((lane >> 3) << 4);  // swizzled byte col

    short8 kst[2], vst[2];
#define STAGE_LOAD(kb_) do {                                                     \
    int nb_ = (kb_);                                                             \
    _Pragma("unroll") for (int ci = 0; ci < 2; ci++) {                           \
        int r_ = srow + ci * 8;                                                  \
        kst[ci] = *reinterpret_cast<const short8*>(Kp + (size_t)(nb_ + r_) * D_ + scol); \
        vst[ci] = *reinterpret_cast<const short8*>(Vp + (size_t)r_ * S_ + nb_ + scol);   \
    } } while (0)
#define STAGE_WRITE(d_) do {                                                     \
    _Pragma("unroll") for (int ci = 0; ci < 2; ci++) {                           \
        int r_ = srow + ci * 8;                                                  \
        *reinterpret_cast<short8*>((char*)kbuf[d_] + r_ * 128 + swz) = kst[ci];  \
        *reinterpret_cast<short8*>((char*)vbuf[d_] + r_ * 128 + swz) = vst[ci];  \
    } } while (0)

    STAGE_LOAD(0);
    STAGE_WRITE(0);
    __syncthreads();
    int cur = 0;

    for (int kt = 0; kt < 64; ++kt) {
        if (kt < 63) STAGE_LOAD((kt + 1) * 64);   // T14: issue early

        f32x16 s0, s1;
#pragma unroll
        for (int r = 0; r < 16; r++) { s0[r] = 0.f; s1[r] = 0.f; }
#pragma unroll
        for (int ds = 0; ds < 4; ds++) {
            short8 k0 = lds_rd(kbuf[cur], l31,      ds * 32 + hi * 16);
            short8 k1 = lds_rd(kbuf[cur], 32 + l31, ds * 32 + hi * 16);
            s0 = __builtin_amdgcn_mfma_f32_32x32x16_bf16(k0, qf[ds], s0, 0, 0, 0);
            s1 = __builtin_amdgcn_mfma_f32_32x32x16_bf16(k1, qf[ds], s1, 0, 0, 0);
        }
        // p = exp2(s); 4 independent partial-sum chains (r&3 is compile-time)
#pragma unroll
        for (int r = 0; r < 16; r++) { s0[r] = __builtin_amdgcn_exp2f(s0[r]); lacc[r & 3] += s0[r]; }
#pragma unroll
        for (int r = 0; r < 16; r++) { s1[r] = __builtin_amdgcn_exp2f(s1[r]); lacc[r & 3] += s1[r]; }

        int w[16];
#pragma unroll
        for (int t = 0; t < 8; t++) {
            asm("v_cvt_pk_bf16_f32 %0, %1, %2" : "=v"(w[t])     : "v"(s0[2 * t]), "v"(s0[2 * t + 1]));
            asm("v_cvt_pk_bf16_f32 %0, %1, %2" : "=v"(w[8 + t]) : "v"(s1[2 * t]), "v"(s1[2 * t + 1]));
        }
        short8 pf[4];
#pragma unroll
        for (int g = 0; g < 4; g++) {
            int a0 = w[g * 4 + 0], b0 = w[g * 4 + 2];
            int a1 = w[g * 4 + 1], b1 = w[g * 4 + 3];
            asm("v_permlane32_swap_b32 %0, %1" : "+v"(a0), "+v"(b0));
            asm("v_permlane32_swap_b32 %0, %1" : "+v"(a1), "+v"(b1));
            i32x4 t4 = {a0, a1, b0, b1};
            pf[g] = __builtin_bit_cast(short8, t4);
        }
#pragma unroll
        for (int ks = 0; ks < 4; ks++) {
            short8 v0 = lds_rd(vbuf[cur], l31,      ks * 32 + hi * 16);
            short8 v1 = lds_rd(vbuf[cur], 32 + l31, ks * 32 + hi * 16);
            ctx0 = __builtin_amdgcn_mfma_f32_32x32x16_bf16(v0, pf[ks], ctx0, 0, 0, 0);
            ctx1 = __builtin_amdgcn_mfma_f32_32x32x16_bf16(v1, pf[ks], ctx1, 0, 0, 0);
        }
        if (kt < 63) STAGE_WRITE(cur ^ 1);        // T14: write late
        __syncthreads();
        cur ^= 1;
    }

    float lsum = (lacc[0] + lacc[1]) + (lacc[2] + lacc[3]);
    float l_run = lsum + __shfl_xor(lsum, 32);
    float invl = 1.0f / l_run;
    short* obw = &ob[wv][0];
#pragma unroll
    for (int n = 0; n < 2; n++) {
#pragma unroll
        for (int t = 0; t < 8; t++) {
            float a  = (n ? ctx1[2 * t]     : ctx0[2 * t])     * invl;
            float bb = (n ? ctx1[2 * t + 1] : ctx0[2 * t + 1]) * invl;
            int wd;
            asm("v_cvt_pk_bf16_f32 %0, %1, %2" : "=v"(wd) : "v"(a), "v"(bb));
            int d = n * 32 + ((2 * t) & 3) + 8 * ((2 * t) >> 2) + 4 * hi;
            *reinterpret_cast<int*>(obw + l31 * 72 + d) = wd;
        }
    }
    __syncthreads();
    {
        int q = lane >> 1, half = lane & 1;
        size_t gbase = ((size_t)b * S_ + qrow0 + q) * E_ + h * 64 + half * 32;
#pragma unroll
        for (int j = 0; j < 4; j++) {
            short8 vvv = *reinterpret_cast<const short8*>(obw + q * 72 + half * 32 + j * 8);
            *reinterpret_cast<short8*>(ctxb + gbase + j * 8) = vvv;
        }
    }
    if (lane < 32)
        Lrow[(size_t)bh * S_ + qrow0 + lane] = l_run;
#undef STAGE_LOAD
#undef STAGE_WRITE
}

// ---------------------------------------------------------------------------
// pass 2 (v8, r12 form): Q AND K LDS-staged (coalesced, dbuf, XOR swizzle).
// ---------------------------------------------------------------------------
__global__ __launch_bounds__(256) void k_weights(
    const short* __restrict__ Qh, const short* __restrict__ Kh,
    const float* __restrict__ Lrow,
    float* __restrict__ outw) {
    __shared__ short Kt[2][64 * 64];         // 8 KB each
    __shared__ short Qt[2][128 * 64];        // 16 KB each
    __shared__ float c_lds[1024];            // 4 KB  [h][128 q]
    int tid = threadIdx.x, lane = tid & 63, wv = tid >> 6;
    int l31 = lane & 31, hi = lane >> 5;
    int gid = blockIdx.x;
    int kc = gid & 63, qt = (gid >> 6) & 31, b = gid >> 11;
    int k0 = kc * 64;
    int qblk = qt * 128;
    int qrow0 = qblk + wv * 32;

    {
        int e0 = tid * 4;                    // 0..1023
        int hh = e0 >> 7, qq = e0 & 127;
        size_t base = ((size_t)(b * H_ + hh)) * S_ + qblk + qq;
        f32x4 lv = *reinterpret_cast<const f32x4*>(&Lrow[base]);
        f32x4 cc;
#pragma unroll
        for (int j = 0; j < 4; j++) cc[j] = -3.0f - __log2f(lv[j]);
        *reinterpret_cast<f32x4*>(&c_lds[e0]) = cc;
    }

    int srow8 = lane >> 3;                   // 0..7 (== staged row & 7)
    int scol  = (lane & 7) * 8;              // source col, shorts
    int swz   = (scol * 2) ^ (srow8 << 4);   // swizzled dest byte col

    const short* Kbase = Kh + ((size_t)(b * H_) * S_ + k0) * D_;     // + h*S*D
    const short* Qbase = Qh + ((size_t)(b * H_) * S_ + qblk) * D_;   // + h*S*D

    short8 kst[2], qst[4];
#pragma unroll
    for (int ci = 0; ci < 2; ci++)
        kst[ci] = *reinterpret_cast<const short8*>(
            Kbase + (size_t)(wv * 16 + ci * 8 + srow8) * D_ + scol);
#pragma unroll
    for (int ci = 0; ci < 4; ci++)
        qst[ci] = *reinterpret_cast<const short8*>(
            Qbase + (size_t)(wv * 32 + ci * 8 + srow8) * D_ + scol);
#pragma unroll
    for (int ci = 0; ci < 2; ci++)
        *reinterpret_cast<short8*>((char*)Kt[0] + (wv * 16 + ci * 8 + srow8) * 128 + swz) = kst[ci];
#pragma unroll
    for (int ci = 0; ci < 4; ci++)
        *reinterpret_cast<short8*>((char*)Qt[0] + (wv * 32 + ci * 8 + srow8) * 128 + swz) = qst[ci];
    __syncthreads();

    f32x16 w0, w1;
#pragma unroll
    for (int r = 0; r < 16; r++) { w0[r] = 0.f; w1[r] = 0.f; }

    int cur = 0;
    for (int h = 0; h < H_; ++h) {
        if (h < 7) {   // T14: issue next head's staging loads early (coalesced)
            const short* kp = Kbase + (size_t)(h + 1) * S_ * D_;
            const short* qp = Qbase + (size_t)(h + 1) * S_ * D_;
#pragma unroll
            for (int ci = 0; ci < 2; ci++)
                kst[ci] = *reinterpret_cast<const short8*>(
                    kp + (size_t)(wv * 16 + ci * 8 + srow8) * D_ + scol);
#pragma unroll
            for (int ci = 0; ci < 4; ci++)
                qst[ci] = *reinterpret_cast<const short8*>(
                    qp + (size_t)(wv * 32 + ci * 8 + srow8) * D_ + scol);
        }
        f32x16 s0, s1;
#pragma unroll
        for (int g = 0; g < 4; g++) {
            f32x4 ci4 = *reinterpret_cast<const f32x4*>(
                &c_lds[h * 128 + wv * 32 + 4 * hi + 8 * g]);
#pragma unroll
            for (int j = 0; j < 4; j++) { s0[g * 4 + j] = ci4[j]; s1[g * 4 + j] = ci4[j]; }
        }
#pragma unroll
        for (int ks = 0; ks < 4; ks++) {
            short8 aq = lds_rd(Qt[cur], wv * 32 + l31, ks * 32 + hi * 16);
            short8 b0 = lds_rd(Kt[cur], l31,           ks * 32 + hi * 16);
            short8 b1 = lds_rd(Kt[cur], 32 + l31,      ks * 32 + hi * 16);
            s0 = __builtin_amdgcn_mfma_f32_32x32x16_bf16(aq, b0, s0, 0, 0, 0);
            s1 = __builtin_amdgcn_mfma_f32_32x32x16_bf16(aq, b1, s1, 0, 0, 0);
        }
#pragma unroll
        for (int r = 0; r < 16; r++) {
            w0[r] += __builtin_amdgcn_exp2f(s0[r]);
            w1[r] += __builtin_amdgcn_exp2f(s1[r]);
        }
        if (h < 7) {
#pragma unroll
            for (int ci = 0; ci < 2; ci++)
                *reinterpret_cast<short8*>((char*)Kt[cur ^ 1] + (wv * 16 + ci * 8 + srow8) * 128 + swz) = kst[ci];
#pragma unroll
            for (int ci = 0; ci < 4; ci++)
                *reinterpret_cast<short8*>((char*)Qt[cur ^ 1] + (wv * 32 + ci * 8 + srow8) * 128 + swz) = qst[ci];
        }
        __syncthreads();
        cur ^= 1;
    }
#pragma unroll
    for (int r = 0; r < 16; r++) {
        int qrow = qrow0 + (r & 3) + 8 * (r >> 2) + 4 * hi;
        float* op = outw + ((size_t)b * S_ + qrow) * (size_t)S_ + k0;
        op[l31]      = w0[r];
        op[32 + l31] = w1[r];
    }
}

// ---------------------------------------------------------------------------
extern "C" void kernel_launch(void* const* d_in, const int* in_sizes, int n_in,
                              void* d_out, int out_size, void* d_ws, size_t ws_size,
                              hipStream_t stream) {
    (void)in_sizes; (void)n_in; (void)out_size; (void)ws_size;
    const float* q     = (const float*)d_in[0];
    const float* k     = (const float*)d_in[1];
    const float* v     = (const float*)d_in[2];
    const float* in_w  = (const float*)d_in[3];
    const float* in_b  = (const float*)d_in[4];
    const float* out_w = (const float*)d_in[5];
    const float* out_b = (const float*)d_in[6];
    float* out  = (float*)d_out;
    float* outw = out + (size_t)B_ * S_ * E_;

    char* ws = (char*)d_ws;
    size_t off = 0;
    auto alloc = [&](size_t bytes) { void* p = ws + off; off += (bytes + 255) & ~(size_t)255; return p; };

    float2* cs   = (float2*)alloc((size_t)S_ * 256 * 8);          //  8.4 MB
    short*  Aq   = (short*) alloc((size_t)BS_ * E_ * 2);          //  8.4 MB
    short*  Ak   = (short*) alloc((size_t)BS_ * E_ * 2);          //  8.4 MB
    short*  Av   = (short*) alloc((size_t)BS_ * E_ * 2);          //  8.4 MB
    short*  Wall = (short*) alloc((size_t)3 * E_ * E_ * 2);       //  1.6 MB (Wq|Wk|Wv)
    short*  Wo   = (short*) alloc((size_t)E_ * E_ * 2);           //  0.5 MB
    short*  Qh   = (short*) alloc((size_t)B_ * H_ * S_ * D_ * 2); //  8.4 MB
    short*  Kh   = (short*) alloc((size_t)B_ * H_ * S_ * D_ * 2); //  8.4 MB
    short*  Vt   = (short*) alloc((size_t)B_ * H_ * D_ * S_ * 2); //  8.4 MB
    short*  ctxb = (short*) alloc((size_t)BS_ * E_ * 2);          //  8.4 MB
    float*  Lrow = (float*) alloc((size_t)B_ * H_ * S_ * 4);

    k_cstable<<<S_, 256, 0, stream>>>(cs);
    k_rope2<<<dim3(BS_, 2), 256, 0, stream>>>(q, k, cs, Aq, Ak);
    k_cast3<<<(NV8 + NW18 + NW28 + 255) / 256, 256, 0, stream>>>(v, in_w, out_w, Av, Wall, Wo);

    k_gemm_qkv<<<dim3(E_ / 128, BS_ / 128, 3), 256, 0, stream>>>(
        Aq, Ak, Av, Wall, in_b, Qh, Kh, Vt);
    k_flash<<<B_ * H_ * (S_ / 128), 256, 0, stream>>>(Qh, Kh, Vt, ctxb, Lrow);
    k_gemm_out<<<dim3(E_ / 128, BS_ / 128), 256, 0, stream>>>(ctxb, Wo, out_b, out);
    k_weights<<<B_ * (S_ / 128) * (S_ / 64), 256, 0, stream>>>(Qh, Kh, Lrow, outw);
}